// Round 7
// baseline (841.090 us; speedup 1.0000x reference)
//
#include <hip/hip_runtime.h>
#include <stdint.h>

typedef __bf16 bf16x8 __attribute__((ext_vector_type(8)));
typedef float  f32x4  __attribute__((ext_vector_type(4)));

#define F_TOT 8192
#define DIM   1024
#define NEXP  8
#define FF    4096
#define CAP   2560

__device__ __forceinline__ float b2f(unsigned short u){
    union { unsigned int u; float f; } c; c.u = ((unsigned int)u) << 16; return c.f;
}
__device__ __forceinline__ unsigned short f2b(float f){
    union { float f; unsigned int u; } c; c.f = f;
    unsigned int r = c.u + 0x7FFFu + ((c.u >> 16) & 1u);
    return (unsigned short)(r >> 16);
}
__device__ __forceinline__ float ldIn(const void* p, size_t i, int isb){
    return isb ? b2f(((const unsigned short*)p)[i]) : ((const float*)p)[i];
}
__device__ __forceinline__ void gl_lds16(const unsigned short* g, unsigned short* l){
    __builtin_amdgcn_global_load_lds(
        (const __attribute__((address_space(1))) unsigned int*)(g),
        (__attribute__((address_space(3))) unsigned int*)(l),
        16, 0, 0);
}

// ---------------- fused: detect + gating + route + convx --------------------
// 512 blocks x 256 threads; block g owns tokens [16g, 16g+16).
// When input is already bf16, the convx copy is skipped (ffn0 reads x direct).
__global__ __launch_bounds__(256)
void gating_kernel(const void* __restrict__ x,
                   const void* __restrict__ noise,
                   const void* __restrict__ Wg, const void* __restrict__ bg,
                   const void* __restrict__ Wn, const void* __restrict__ bn,
                   int* __restrict__ flag,
                   int* __restrict__ topi, float* __restrict__ gates,
                   unsigned short* __restrict__ xb)
{
    __shared__ int sflag;
    __shared__ float lg[16][17];     // [token][0..7 logits | 8..15 noise-logits]
    const int g = blockIdx.x, tid = threadIdx.x;
    const unsigned short* xs = (const unsigned short*)x;

    // ---- detect (replicates original 512-sample test per block) ----
    if (tid == 0) sflag = 0;
    __syncthreads();
    {
        int c = 0;
        unsigned short s0 = xs[tid], s1 = xs[tid + 256];
        int e0 = s0 & 0x7F80, e1 = s1 & 0x7F80;
        if (e0 >= 0x3000 && e0 <= 0x4800) c++;
        if (e1 >= 0x3000 && e1 <= 0x4800) c++;
        if (c) atomicAdd(&sflag, c);
    }
    __syncthreads();
    const int isb = (sflag >= 410) ? 1 : 0;
    if (g == 0 && tid == 0) flag[0] = isb;

    // ---- gating dot: 16 tokens x 16 outputs (8 logit + 8 noise-logit) ----
    const int tl = tid >> 4, o = tid & 15, col = o & 7;
    const int t = g * 16 + tl;
    const void* W = (o < 8) ? Wg : Wn;
    float acc = 0.f;
    if (isb){
        const unsigned short* xr = xs + (size_t)t * DIM;
        const unsigned short* w  = (const unsigned short*)W;
        for (int d = 0; d < DIM; d += 8){
            ushort4 a = *(const ushort4*)(xr + d);
            ushort4 b = *(const ushort4*)(xr + d + 4);
            acc = fmaf(b2f(a.x), b2f(w[(d+0)*8+col]), acc);
            acc = fmaf(b2f(a.y), b2f(w[(d+1)*8+col]), acc);
            acc = fmaf(b2f(a.z), b2f(w[(d+2)*8+col]), acc);
            acc = fmaf(b2f(a.w), b2f(w[(d+3)*8+col]), acc);
            acc = fmaf(b2f(b.x), b2f(w[(d+4)*8+col]), acc);
            acc = fmaf(b2f(b.y), b2f(w[(d+5)*8+col]), acc);
            acc = fmaf(b2f(b.z), b2f(w[(d+6)*8+col]), acc);
            acc = fmaf(b2f(b.w), b2f(w[(d+7)*8+col]), acc);
        }
    } else {
        const float* xr = (const float*)x + (size_t)t * DIM;
        const float* w  = (const float*)W;
        for (int d = 0; d < DIM; d += 8){
            float4 a = *(const float4*)(xr + d);
            float4 b = *(const float4*)(xr + d + 4);
            acc = fmaf(a.x, w[(d+0)*8+col], acc);
            acc = fmaf(a.y, w[(d+1)*8+col], acc);
            acc = fmaf(a.z, w[(d+2)*8+col], acc);
            acc = fmaf(a.w, w[(d+3)*8+col], acc);
            acc = fmaf(b.x, w[(d+4)*8+col], acc);
            acc = fmaf(b.y, w[(d+5)*8+col], acc);
            acc = fmaf(b.z, w[(d+6)*8+col], acc);
            acc = fmaf(b.w, w[(d+7)*8+col], acc);
        }
    }
    acc += ldIn((o < 8) ? bg : bn, col, isb);
    lg[tl][o] = acc;
    __syncthreads();

    // ---- route (one thread per token) ----
    if (tid < 16){
        const int tt = g * 16 + tid;
        float ny[8];
        #pragma unroll
        for (int e = 0; e < 8; e++){
            float nl = lg[tid][8 + e];
            float sp = fmaxf(nl, 0.f) + log1pf(expf(-fabsf(nl)));
            ny[e] = lg[tid][e] + ldIn(noise, (size_t)tt * 8 + e, isb) * sp;
        }
        int i0 = 0; float v0 = ny[0];
        #pragma unroll
        for (int e = 1; e < 8; e++) if (ny[e] > v0){ v0 = ny[e]; i0 = e; }
        int i1 = -1; float v1 = -3.4e38f;
        #pragma unroll
        for (int e = 0; e < 8; e++) if (e != i0 && ny[e] > v1){ v1 = ny[e]; i1 = e; }
        float e1 = expf(v1 - v0);
        float den = 1.f + e1;
        topi[tt * 2]      = i0;  topi[tt * 2 + 1] = i1;
        gates[tt * 2]     = 1.f / den;
        gates[tt * 2 + 1] = e1 / den;
    }

    // ---- convx: only needed for fp32 input (bf16 input is read directly) ----
    if (!isb){
        const size_t base = (size_t)g * 16384;
        #pragma unroll
        for (int it = 0; it < 8; it++){
            size_t i = base + (size_t)it * 2048 + tid * 8;
            float4 a = *(const float4*)((const float*)x + i);
            float4 b = *(const float4*)((const float*)x + i + 4);
            ushort4 lo, hi;
            lo.x = f2b(a.x); lo.y = f2b(a.y); lo.z = f2b(a.z); lo.w = f2b(a.w);
            hi.x = f2b(b.x); hi.y = f2b(b.y); hi.z = f2b(b.z); hi.w = f2b(b.w);
            *(ushort4*)(xb + i) = lo; *(ushort4*)(xb + i + 4) = hi;
        }
    }
}

// ---------------- scan: dispatch[e][pos]=t, slotf[t][k]=e*CAP+pos, cnt[e] ---
__global__ __launch_bounds__(1024)
void scan_kernel(const int* __restrict__ topi,
                 int* __restrict__ dispatch, int* __restrict__ slotf,
                 int* __restrict__ cntbuf)
{
    int e = blockIdx.x;
    int tid = threadIdx.x;
    for (int c = tid; c < CAP; c += 1024) dispatch[e * CAP + c] = F_TOT;
    int base = tid * 8;
    int kk[8]; int cnt = 0;
    #pragma unroll
    for (int j = 0; j < 8; j++){
        int t = base + j;
        int k = (topi[t * 2] == e) ? 0 : ((topi[t * 2 + 1] == e) ? 1 : -1);
        kk[j] = k; if (k >= 0) cnt++;
    }
    __shared__ int s[1024];
    s[tid] = cnt; __syncthreads();
    for (int off = 1; off < 1024; off <<= 1){
        int v = (tid >= off) ? s[tid - off] : 0;
        __syncthreads();
        s[tid] += v;
        __syncthreads();
    }
    if (tid == 1023){ int tot = s[1023]; cntbuf[e] = tot > CAP ? CAP : tot; }
    int pos = s[tid] - cnt;
    #pragma unroll
    for (int j = 0; j < 8; j++){
        if (kk[j] >= 0){
            int t = base + j;
            if (pos < CAP){
                dispatch[e * CAP + pos] = t;
                slotf[t * 2 + kk[j]] = e * CAP + pos;
            } else {
                slotf[t * 2 + kk[j]] = -1;     // dropped (over capacity)
            }
            pos++;
        }
    }
}

// ---------------- transpose (dual-dtype in, bf16 out) -----------------------
__global__ void transpose_kernel(const void* __restrict__ in,
                                 unsigned short* __restrict__ out,
                                 const int* __restrict__ flag,
                                 int R, int C, int eBase)
{
    __shared__ unsigned short tile[64][68];
    const size_t mi = (size_t)(eBase + blockIdx.z) * R * C;
    const size_t mo = (size_t)blockIdx.z * R * C;
    int c0 = blockIdx.x * 64, r0 = blockIdx.y * 64;
    int t = threadIdx.x;
    int rr = t >> 4, cc = (t & 15) * 4;
    int isb = flag[0];
    #pragma unroll
    for (int i = 0; i < 4; i++){
        int r = rr + i * 16;
        size_t idx = mi + (size_t)(r0 + r) * C + c0 + cc;
        if (isb){
            ushort4 v = *(const ushort4*)((const unsigned short*)in + idx);
            *(ushort4*)&tile[r][cc] = v;
        } else {
            float4 v = *(const float4*)((const float*)in + idx);
            ushort4 u; u.x = f2b(v.x); u.y = f2b(v.y); u.z = f2b(v.z); u.w = f2b(v.w);
            *(ushort4*)&tile[r][cc] = u;
        }
    }
    __syncthreads();
    #pragma unroll
    for (int i = 0; i < 4; i++){
        int c = rr + i * 16;
        ushort4 v;
        v.x = tile[cc + 0][c]; v.y = tile[cc + 1][c];
        v.z = tile[cc + 2][c]; v.w = tile[cc + 3][c];
        *(ushort4*)(out + mo + (size_t)(c0 + c) * R + r0 + cc) = v;
    }
}

// ---------------- ffn0: h = gelu(gather(x)@W1t^T + b1) ----------------------
// Linear grid (nt fastest): A (=x/xb, 16.8MB) is L3-resident, no clustering.
// grid: x = 32*20, y = EPG experts
__global__ __launch_bounds__(256, 2)
void ffn0_kernel(const unsigned short* __restrict__ xraw,
                 const unsigned short* __restrict__ xb,
                 const unsigned short* __restrict__ Wt,   // [EPG][FF][DIM]
                 const void* __restrict__ b1,
                 const int* __restrict__ flag,
                 unsigned short* __restrict__ h,          // [EPG][CAP][FF]
                 const int* __restrict__ dispatch,
                 const int* __restrict__ cnt, int eBase)
{
    constexpr int KT = DIM, NT = FF, NTILES = NT / 128;
    const int el = blockIdx.y, eg = el + eBase;
    const int nt = blockIdx.x % NTILES;
    const int mt = blockIdx.x / NTILES;
    const int m0 = mt * 128, n0 = nt * 128;
    if (m0 >= cnt[eg]) return;               // m-tile fully past expert rows
    const int tid = threadIdx.x, lane = tid & 63, wave = tid >> 6;
    const int wm = wave >> 1, wn = wave & 1;
    const int quad = lane >> 4, l16 = lane & 15;

    __shared__ __align__(16) unsigned short As[128 * 32];
    __shared__ __align__(16) unsigned short Bs[128 * 32];

    const unsigned short* xsrc = flag[0] ? xraw : xb;

    const int r0 = tid >> 2, c8 = (tid & 3) * 8;
    int t0 = dispatch[eg * CAP + m0 + r0];
    int t1 = dispatch[eg * CAP + m0 + 64 + r0];
    bool v0 = ((unsigned)t0) < (unsigned)F_TOT;
    bool v1 = ((unsigned)t1) < (unsigned)F_TOT;
    const unsigned short* aS0 = xsrc + (v0 ? (size_t)t0 * DIM : 0) + c8;
    const unsigned short* aS1 = xsrc + (v1 ? (size_t)t1 * DIM : 0) + c8;
    const unsigned short* bE  = Wt + (size_t)el * NT * KT;
    const unsigned short* bS0 = bE + (size_t)(n0 + r0) * KT + c8;
    const unsigned short* bS1 = bE + (size_t)(n0 + 64 + r0) * KT + c8;

    f32x4 acc[4][4] = {};

    for (int k0 = 0; k0 < KT; k0 += 32){
        __syncthreads();
        gl_lds16(aS0, &As[tid * 8]);
        gl_lds16(aS1, &As[2048 + tid * 8]);
        gl_lds16(bS0, &Bs[tid * 8]);
        gl_lds16(bS1, &Bs[2048 + tid * 8]);
        aS0 += 32; aS1 += 32; bS0 += 32; bS1 += 32;
        __syncthreads();

        bf16x8 af[4], bfv[4];
        #pragma unroll
        for (int i = 0; i < 4; i++)
            af[i] = *(const bf16x8*)&As[(wm * 64 + i * 16 + l16) * 32 + quad * 8];
        #pragma unroll
        for (int j = 0; j < 4; j++)
            bfv[j] = *(const bf16x8*)&Bs[(wn * 64 + j * 16 + l16) * 32 + quad * 8];
        #pragma unroll
        for (int i = 0; i < 4; i++)
            #pragma unroll
            for (int j = 0; j < 4; j++)
                acc[i][j] = __builtin_amdgcn_mfma_f32_16x16x32_bf16(af[i], bfv[j], acc[i][j], 0, 0, 0);
    }

    const int isb = flag[0];
    const int rB = m0 + wm * 64 + quad * 4;
    const int cB = n0 + wn * 64 + l16;
    float bv[4];
    #pragma unroll
    for (int j = 0; j < 4; j++) bv[j] = ldIn(b1, (size_t)eg * NT + cB + j * 16, isb);
    #pragma unroll
    for (int i = 0; i < 4; i++)
        #pragma unroll
        for (int j = 0; j < 4; j++)
            #pragma unroll
            for (int r = 0; r < 4; r++){
                int row = rB + i * 16 + r;
                float v = acc[i][j][r] + bv[j];
                v = 0.5f * v * (1.0f + erff(v * 0.70710678118654752f));
                h[((size_t)(el * CAP + row)) * FF + cB + j * 16] = f2b(v);
            }
}

// ---------------- ffn1: eo[eg][slot] = h@W2t^T + b2 -------------------------
// XCD-clustered: A (=h) is not L3-resident; the 8 nt-blocks sharing one
// (expert, mt) A-panel are co-located on one XCD (round 5: FETCH 323->181MB).
// grid: x = 8 * 3 * 8 = 192, y = EPG experts
__global__ __launch_bounds__(256, 2)
void ffn1_kernel(const unsigned short* __restrict__ h,    // [EPG][CAP][FF]
                 const unsigned short* __restrict__ Wt,   // [EPG][DIM][FF]
                 const void* __restrict__ b2,
                 const int* __restrict__ flag,
                 unsigned short* __restrict__ eo,         // [8][CAP][DIM]
                 const int* __restrict__ cnt, int eBase)
{
    constexpr int KT = FF, NT = DIM, NTILES = NT / 128;
    const int el = blockIdx.y, eg = el + eBase;
    const int p = blockIdx.x;
    const int xcd = p & 7, s = p >> 3;
    const int nt = s % NTILES;
    const int mt = xcd + 8 * (s / NTILES);
    if (mt >= CAP / 128) return;
    const int m0 = mt * 128, n0 = nt * 128;
    if (m0 >= cnt[eg]) return;               // m-tile fully past expert rows
    const int tid = threadIdx.x, lane = tid & 63, wave = tid >> 6;
    const int wm = wave >> 1, wn = wave & 1;
    const int quad = lane >> 4, l16 = lane & 15;

    __shared__ __align__(16) unsigned short As[128 * 32];
    __shared__ __align__(16) unsigned short Bs[128 * 32];

    const int r0 = tid >> 2, c8 = (tid & 3) * 8;
    const unsigned short* aS0 = h + ((size_t)(el * CAP + m0 + r0)) * KT + c8;
    const unsigned short* aS1 = h + ((size_t)(el * CAP + m0 + 64 + r0)) * KT + c8;
    const unsigned short* bE  = Wt + (size_t)el * NT * KT;
    const unsigned short* bS0 = bE + (size_t)(n0 + r0) * KT + c8;
    const unsigned short* bS1 = bE + (size_t)(n0 + 64 + r0) * KT + c8;

    f32x4 acc[4][4] = {};

    for (int k0 = 0; k0 < KT; k0 += 32){
        __syncthreads();
        gl_lds16(aS0, &As[tid * 8]);
        gl_lds16(aS1, &As[2048 + tid * 8]);
        gl_lds16(bS0, &Bs[tid * 8]);
        gl_lds16(bS1, &Bs[2048 + tid * 8]);
        aS0 += 32; aS1 += 32; bS0 += 32; bS1 += 32;
        __syncthreads();

        bf16x8 af[4], bfv[4];
        #pragma unroll
        for (int i = 0; i < 4; i++)
            af[i] = *(const bf16x8*)&As[(wm * 64 + i * 16 + l16) * 32 + quad * 8];
        #pragma unroll
        for (int j = 0; j < 4; j++)
            bfv[j] = *(const bf16x8*)&Bs[(wn * 64 + j * 16 + l16) * 32 + quad * 8];
        #pragma unroll
        for (int i = 0; i < 4; i++)
            #pragma unroll
            for (int j = 0; j < 4; j++)
                acc[i][j] = __builtin_amdgcn_mfma_f32_16x16x32_bf16(af[i], bfv[j], acc[i][j], 0, 0, 0);
    }

    const int isb = flag[0];
    const int rB = m0 + wm * 64 + quad * 4;
    const int cB = n0 + wn * 64 + l16;
    float bv[4];
    #pragma unroll
    for (int j = 0; j < 4; j++) bv[j] = ldIn(b2, (size_t)eg * NT + cB + j * 16, isb);
    #pragma unroll
    for (int i = 0; i < 4; i++)
        #pragma unroll
        for (int j = 0; j < 4; j++)
            #pragma unroll
            for (int r = 0; r < 4; r++){
                int row = rB + i * 16 + r;
                eo[((size_t)(eg * CAP + row)) * DIM + cB + j * 16] = f2b(acc[i][j][r] + bv[j]);
            }
}

// ---------------- combine: out[t] = g0*eo[s0] + g1*eo[s1] -------------------
__global__ void combine_kernel(const unsigned short* __restrict__ eo,
                               const int* __restrict__ slotf,
                               const float* __restrict__ gates,
                               const int* __restrict__ flag,
                               void* __restrict__ out)
{
    int t = blockIdx.x;
    int d = threadIdx.x * 4;
    int s0 = slotf[t * 2], s1 = slotf[t * 2 + 1];
    float g0 = gates[t * 2], g1 = gates[t * 2 + 1];
    float a0 = 0.f, a1 = 0.f, a2 = 0.f, a3 = 0.f;
    if (((unsigned)s0) < (unsigned)(NEXP * CAP)){
        ushort4 a = *(const ushort4*)(eo + (size_t)s0 * DIM + d);
        a0 += g0 * b2f(a.x); a1 += g0 * b2f(a.y);
        a2 += g0 * b2f(a.z); a3 += g0 * b2f(a.w);
    }
    if (((unsigned)s1) < (unsigned)(NEXP * CAP)){
        ushort4 a = *(const ushort4*)(eo + (size_t)s1 * DIM + d);
        a0 += g1 * b2f(a.x); a1 += g1 * b2f(a.y);
        a2 += g1 * b2f(a.z); a3 += g1 * b2f(a.w);
    }
    if (flag[0]){
        ushort4 o; o.x = f2b(a0); o.y = f2b(a1); o.z = f2b(a2); o.w = f2b(a3);
        *(ushort4*)((unsigned short*)out + (size_t)t * DIM + d) = o;
    } else {
        float4 o; o.x = a0; o.y = a1; o.z = a2; o.w = a3;
        *(float4*)((float*)out + (size_t)t * DIM + d) = o;
    }
}

// ---------------- launch ----------------------------------------------------
extern "C" void kernel_launch(void* const* d_in, const int* in_sizes, int n_in,
                              void* d_out, int out_size, void* d_ws, size_t ws_size,
                              hipStream_t stream)
{
    const void* x     = d_in[0];
    const void* noise = d_in[1];
    const void* Wg    = d_in[2];
    const void* bg    = d_in[3];
    const void* Wn    = d_in[4];
    const void* bn    = d_in[5];
    const void* W1    = d_in[6];
    const void* b1    = d_in[7];
    const void* W2    = d_in[8];
    const void* b2    = d_in[9];
    char* ws = (char*)d_ws;

    int*   topi    = (int*)  (ws + 524288);       // 65536
    float* gates   = (float*)(ws + 589824);       // 65536
    int*   disp    = (int*)  (ws + 655360);       // 81920
    int*   slotf   = (int*)  (ws + 737280);       // 65536
    int*   flag    = (int*)  (ws + 802816);       // 4
    int*   cnt     = (int*)  (ws + 803072);       // 32

    // workspace-gated expert batching: 8-at-once needs ~295MB, else 2x4.
    const size_t NEED8 = 294649856ULL;
    const int EPG = (ws_size >= NEED8) ? 8 : 4;

    unsigned short* xb = (unsigned short*)(ws + 1048576);    // 16,777,216
    unsigned short* Wt = (unsigned short*)(ws + 17825792);   // EPG*FF*DIM*2
    unsigned short* h  = Wt + (size_t)EPG * FF * DIM;        // EPG*CAP*FF*2
    unsigned short* eo = h  + (size_t)EPG * CAP * FF;        // 8*CAP*DIM*2

    gating_kernel<<<512, 256, 0, stream>>>(x, noise, Wg, bg, Wn, bn,
                                           flag, topi, gates, xb);
    scan_kernel<<<8, 1024, 0, stream>>>(topi, disp, slotf, cnt);

    for (int g = 0; g < 8 / EPG; g++){
        int eB = g * EPG;
        transpose_kernel<<<dim3(64, 16, EPG), 256, 0, stream>>>(W1, Wt, flag, DIM, FF, eB);
        ffn0_kernel<<<dim3((FF/128) * (CAP/128), EPG), 256, 0, stream>>>(
            (const unsigned short*)x, xb, Wt, b1, flag, h, disp, cnt, eB);
        transpose_kernel<<<dim3(16, 64, EPG), 256, 0, stream>>>(W2, Wt, flag, FF, DIM, eB);
        ffn1_kernel<<<dim3(8 * 3 * (DIM/128), EPG), 256, 0, stream>>>(
            h, Wt, b2, flag, eo, cnt, eB);
    }
    combine_kernel<<<F_TOT, 256, 0, stream>>>(eo, slotf, gates, flag, d_out);
}